// Round 10
// baseline (161.646 us; speedup 1.0000x reference)
//
#include <hip/hip_runtime.h>

typedef __attribute__((ext_vector_type(4))) float f32x4;
typedef __attribute__((ext_vector_type(8))) short bf16x8;
typedef long fp8x8;   // 8 packed e4m3 bytes (i64 MFMA operand)

#define NH 4

// round-to-nearest-even f32 -> bf16
static __device__ __forceinline__ unsigned short f2bf(float f){
  unsigned u = __float_as_uint(f);
  u += 0x7FFFu + ((u >> 16) & 1u);
  return (unsigned short)(u >> 16);
}

// pack two f32 -> two bf16 (round-half-up) in one uint (low = a)
static __device__ __forceinline__ unsigned pack2bf(float a, float b){
  return __builtin_amdgcn_perm(__float_as_uint(b) + 0x8000u,
                               __float_as_uint(a) + 0x8000u, 0x07060302u);
}

// pack two f32 -> two bf16 TRUNCATING (1 v_perm). Used only for P: the same
// truncated P feeds both O=P*V and l=P*1, so the truncation bias cancels.
static __device__ __forceinline__ unsigned pack2bf_t(float a, float b){
  return __builtin_amdgcn_perm(__float_as_uint(b), __float_as_uint(a), 0x07060302u);
}

// pack 4 floats into 4 fp8(e4m3) bytes of one int (byte0 = a)
static __device__ __forceinline__ int pack_fp8x4(float a, float b, float c, float d){
  int w = __builtin_amdgcn_cvt_pk_fp8_f32(a, b, 0, false);
  w     = __builtin_amdgcn_cvt_pk_fp8_f32(c, d, w, true);
  return w;
}

// ---------------- weight-prep kernel (unchanged, proven) ----------------
__global__ __launch_bounds__(256) void wprep_kernel(
    const float* __restrict__ Wq, const float* __restrict__ bq,
    const float* __restrict__ Wk, const float* __restrict__ bk,
    const float* __restrict__ Wv,
    unsigned short* __restrict__ WF, float* __restrict__ bias_s, int n)
{
  __shared__ unsigned short wqT[64*72];  // [e][f], stride 72 (16B-aligned rows)
  __shared__ unsigned short wkT[64*72];
  __shared__ unsigned short wvT[16*72];  // [d][f]

  const int t = threadIdx.x;     // 0..255
  const int h = blockIdx.x;
  const float S1 = 0.4246609001f; // sqrt((1/sqrt(64)) * log2(e))
  const int f = t >> 2, eg = t & 3;

  {
    const float4* g = (const float4*)(Wq + h*4096 + f*64 + eg*16);
    #pragma unroll
    for (int p = 0; p < 4; ++p){
      float4 d = g[p];
      int e0 = eg*16 + p*4;
      wqT[(e0+0)*72 + f] = f2bf(d.x * S1);
      wqT[(e0+1)*72 + f] = f2bf(d.y * S1);
      wqT[(e0+2)*72 + f] = f2bf(d.z * S1);
      wqT[(e0+3)*72 + f] = f2bf(d.w * S1);
    }
  }
  {
    const float4* g = (const float4*)(Wk + h*4096 + f*64 + eg*16);
    #pragma unroll
    for (int p = 0; p < 4; ++p){
      float4 d = g[p];
      int e0 = eg*16 + p*4;
      wkT[(e0+0)*72 + f] = f2bf(d.x * S1);
      wkT[(e0+1)*72 + f] = f2bf(d.y * S1);
      wkT[(e0+2)*72 + f] = f2bf(d.z * S1);
      wkT[(e0+3)*72 + f] = f2bf(d.w * S1);
    }
  }
  {
    float4 d = *(const float4*)(Wv + h*1024 + f*16 + eg*4);
    int d0 = eg*4;
    wvT[(d0+0)*72 + f] = f2bf(d.x);
    wvT[(d0+1)*72 + f] = f2bf(d.y);
    wvT[(d0+2)*72 + f] = f2bf(d.z);
    wvT[(d0+3)*72 + f] = f2bf(d.w);
  }
  if (t < 64)       bias_s[h*128 + t] = bq[h*64 + t] * S1;
  else if (t < 128) bias_s[h*128 + t] = bk[h*64 + (t-64)] * S1;
  __syncthreads();

  const int lane = t & 63, w = t >> 6;
  const int quad = lane >> 4, l16 = lane & 15;
  for (int s = w; s < 18; s += 4){
    const unsigned short* src;
    if (s < 8){      int et = s>>1,     ks = s&1;     src = wqT + (et*16+l16)*72 + ks*32 + quad*8; }
    else if (s < 16){int ft = (s-8)>>1, ks = (s-8)&1; src = wkT + (ft*16+l16)*72 + ks*32 + quad*8; }
    else {           int ks = s-16;                   src = wvT + l16*72 + ks*32 + quad*8; }
    uint4 v = *(const uint4*)src;
    *(uint4*)(WF + ((size_t)(h*18 + s)*64 + lane)*8) = v;
  }
}

// ---------------- projection kernel (unchanged, proven) ----------------
__global__ __launch_bounds__(256) void proj_kernel(
    const float* __restrict__ x, const float* __restrict__ bv,
    const unsigned short* __restrict__ WF, const float* __restrict__ bias_s,
    unsigned char* __restrict__ Qfr, unsigned char* __restrict__ Kt,
    unsigned short* __restrict__ Vt, int n)
{
  __shared__ unsigned short xf[8*64*8];  // x frags: [it*2+ks][lane][8bf16]
  __shared__ float bql[64], bkl[64], bvl[16];

  const int t  = threadIdx.x;
  const int h  = blockIdx.y;
  const int r0 = blockIdx.x * 64;

  {
    const int r = t >> 2, cg4 = t & 3;
    const float4* g = (const float4*)(x + (size_t)(r0 + r)*64 + cg4*16);
    float4 a = g[0], b = g[1], c = g[2], d = g[3];
    unsigned u0 = pack2bf(a.x,a.y), u1 = pack2bf(a.z,a.w);
    unsigned u2 = pack2bf(b.x,b.y), u3 = pack2bf(b.z,b.w);
    unsigned u4 = pack2bf(c.x,c.y), u5 = pack2bf(c.z,c.w);
    unsigned u6 = pack2bf(d.x,d.y), u7 = pack2bf(d.z,d.w);
    const int it = r >> 4, l16r = r & 15, ks = cg4 >> 1, q0 = (cg4 & 1)*2;
    uint4* dst0 = (uint4*)(xf + ((it*2+ks)*64 + q0*16     + l16r)*8);
    uint4* dst1 = (uint4*)(xf + ((it*2+ks)*64 + (q0+1)*16 + l16r)*8);
    *dst0 = make_uint4(u0,u1,u2,u3);
    *dst1 = make_uint4(u4,u5,u6,u7);
  }
  if (t < 64)        bql[t]     = bias_s[h*128 + t];
  else if (t < 128)  bkl[t-64]  = bias_s[h*128 + t];
  else if (t < 144)  bvl[t-128] = bv[h*16 + (t-128)];
  __syncthreads();

  const int lane = t & 63, w = t >> 6;
  const int quad = lane >> 4, l16 = lane & 15;

  bf16x8 xa[8];
  #pragma unroll
  for (int i = 0; i < 8; ++i)
    xa[i] = *(const bf16x8*)(xf + (i*64 + lane)*8);

  const unsigned short* WFh = WF + (size_t)h*18*64*8;
  bf16x8 wq0 = *(const bf16x8*)(WFh + ((size_t)(     w*2 + 0)*64 + lane)*8);
  bf16x8 wq1 = *(const bf16x8*)(WFh + ((size_t)(     w*2 + 1)*64 + lane)*8);
  bf16x8 wk0 = *(const bf16x8*)(WFh + ((size_t)(8  + w*2 + 0)*64 + lane)*8);
  bf16x8 wk1 = *(const bf16x8*)(WFh + ((size_t)(8  + w*2 + 1)*64 + lane)*8);
  bf16x8 wv0 = *(const bf16x8*)(WFh + ((size_t)16*64 + lane)*8);
  bf16x8 wv1 = *(const bf16x8*)(WFh + ((size_t)17*64 + lane)*8);

  const f32x4 z = {0.f,0.f,0.f,0.f};
  f32x4 accQ[4] = {z,z,z,z};   // Q^T: rows e (tile w), cols Q-row (tile it)
  f32x4 accK[4] = {z,z,z,z};   // K^T: rows f (tile w), cols key (tile tt)
  f32x4 accV = z;

  #pragma unroll
  for (int it = 0; it < 4; ++it){
    accQ[it] = __builtin_amdgcn_mfma_f32_16x16x32_bf16(wq0, xa[it*2+0], accQ[it], 0,0,0);
    accQ[it] = __builtin_amdgcn_mfma_f32_16x16x32_bf16(wq1, xa[it*2+1], accQ[it], 0,0,0);
  }
  #pragma unroll
  for (int tt = 0; tt < 4; ++tt){
    accK[tt] = __builtin_amdgcn_mfma_f32_16x16x32_bf16(wk0, xa[tt*2+0], accK[tt], 0,0,0);
    accK[tt] = __builtin_amdgcn_mfma_f32_16x16x32_bf16(wk1, xa[tt*2+1], accK[tt], 0,0,0);
  }
  accV = __builtin_amdgcn_mfma_f32_16x16x32_bf16(xa[w*2+0], wv0, accV, 0,0,0);
  accV = __builtin_amdgcn_mfma_f32_16x16x32_bf16(xa[w*2+1], wv1, accV, 0,0,0);

  // ---- Q^T tiles -> Qfr frag bytes
  {
    const int e0 = w*16 + quad*4;
    const float b0 = bql[e0], b1 = bql[e0+1], b2 = bql[e0+2], b3 = bql[e0+3];
    const int qk = (e0 & 31) >> 3, hf = e0 >> 5, boff = (quad & 1) * 4;
    #pragma unroll
    for (int it = 0; it < 4; ++it){
      unsigned o = pack_fp8x4(accQ[it][0]+b0, accQ[it][1]+b1,
                              accQ[it][2]+b2, accQ[it][3]+b3);
      const int T = (r0 >> 4) + it;
      *(unsigned*)(Qfr + (size_t)h*((size_t)n<<6) + (size_t)T*1024
                       + (qk*16 + l16)*16 + hf*8 + boff) = o;
    }
  }
  // ---- K^T tiles -> Kt frag bytes
  {
    const int f0 = w*16 + quad*4;
    const float bk0 = bkl[f0], bk1 = bkl[f0+1], bk2 = bkl[f0+2], bk3 = bkl[f0+3];
    const int qk = (f0 & 31) >> 3, hf = f0 >> 5, boff = (quad & 1) * 4;
    #pragma unroll
    for (int tt = 0; tt < 4; ++tt){
      unsigned o = pack_fp8x4(accK[tt][0]+bk0, accK[tt][1]+bk1,
                              accK[tt][2]+bk2, accK[tt][3]+bk3);
      const int T = (r0 >> 4) + tt;
      *(unsigned*)(Kt + (size_t)h*((size_t)n<<6) + (size_t)T*1024
                      + (qk*16 + l16)*16 + hf*8 + boff) = o;
    }
  }
  // ---- V tile -> Vt (chunk-interleaved: 8B slot in the lane's 16B K=32 frag)
  {
    float bvv = bvl[l16];
    unsigned v01 = pack2bf(accV[0]+bvv, accV[1]+bvv);
    unsigned v23 = pack2bf(accV[2]+bvv, accV[3]+bvv);
    const int T = (r0 >> 4) + w;
    *(uint2*)(Vt + (size_t)h*((size_t)n<<4)
                 + ((size_t)(T>>1)*64 + lane)*8 + (T&1)*4) = make_uint2(v01, v23);
  }
}

// ---------------- flash attention kernel ----------------
// R25: PRODUCER/CONSUMER WAVE SPECIALIZATION. R16-R24 established the attn
// kernel runs at the no-overlap serial sum (matrix ~60k + VALU ~40k cyc/SIMD
// ~= measured 108k); every single-stream overlap lever (SGB, stagger,
// occupancy, fusion, setprio) is null -- consistent with m253 (within-wave
// MFMA||VALU pipelining never beats sequential). BUT m114 (HW-measured):
// an MFMA-only wave and a VALU-only wave on one CU run CONCURRENTLY
// (time ~ max, not sum). This kernel creates exactly that population:
// block = 32 rows, 8 waves = 4 pairs (pair p: row-half p&1, key-half p>>1,
// 128 chunks of 32 keys). m-wave (w<4): QK MFMAs -> S(f32)->LDS; PV+la
// MFMAs from P; all global loads. v-wave (w+4): S->8 exp2+4 packs->P->LDS.
// SAME-LANE exchange (no cross-lane), XOR-swizzled 16B slots, S/P double-
// buffered, 1 barrier/chunk software pipeline:
//   halfA: m computes S(c) || v exps S(c-1)->P ; barrier ; halfB: m PV(c-1).
// Numerics identical to R19 (same ops, same lanes, same order).
// 1024 blocks x 512thr, LDS 28.6KB -> 4 blocks/CU (wave-capped),
// 8 waves/SIMD = 4 MFMA-feeders + 4 VALU-feeders.
__global__ __launch_bounds__(512, 4) void attn_kernel(
    const unsigned char* __restrict__ Qfr, const unsigned char* __restrict__ Kt,
    const unsigned short* __restrict__ Vt, float* __restrict__ out, int n)
{
  __shared__ char xbuf[16384 + 8192];   // S: [2][4][2][1024B], P: [2][4][1024B]
  __shared__ float part[2][64][9];      // cross-key-half partials (o,la)

  char* sbv = xbuf;
  char* pbv = xbuf + 16384;

  const int tid  = threadIdx.x;
  const int lane = tid & 63;
  const int w    = tid >> 6;          // 0..7
  const bool mw  = (w < 4);           // MFMA role
  const int p    = w & 3;             // pair id
  const int rh   = p & 1;             // row-half (i-tile)
  const int kh   = p >> 1;            // key-half

  const int bid  = blockIdx.x;
  const int h    = bid & 3;
  const int iblk = bid >> 2;
  const int l16  = lane & 15, quad = lane >> 4;
  const int i0   = iblk*32;
  const int nch  = n >> 6;            // 32-key chunks per key-half (128)
  const int tile0 = kh * (n >> 5);    // 16-key tile offset of this key-half

  // XOR-swizzle within each 1024B group: lanes {0,8,16,24} land on distinct
  // bank quads -> <=2-way conflict (free, m136).
  const int swz = (lane*16) ^ (((lane>>3)&3) << 4);
  char* sbp = sbv + p*2048 + swz;     // + (buf)*8192 (+1024 for u-group)
  char* pbp = pbv + p*1024 + swz;     // + (buf)*4096

  const f32x4 z = {0.f,0.f,0.f,0.f};
  const bf16x8 vones = {(short)0x3F80, (short)0x3F80, (short)0x3F80, (short)0x3F80,
                        (short)0x3F80, (short)0x3F80, (short)0x3F80, (short)0x3F80};

  // m-wave persistent state
  fp8x8 qf0 = 0, qf1 = 0;
  longlong2 kcA, kcB;
  uint4 vPrev, vCur;
  const longlong2* ktl = nullptr;
  const uint4*     vtu = nullptr;
  f32x4 o = z, la = z;

  if (mw){
    const unsigned char* qfh = Qfr + (size_t)h*((size_t)n<<6);
    longlong2 q = *(const longlong2*)(qfh + (size_t)((i0>>4)+rh)*1024 + lane*16);
    qf0 = (fp8x8)q.x; qf1 = (fp8x8)q.y;
    ktl = (const longlong2*)(Kt + (size_t)h*((size_t)n<<6)) + (size_t)tile0*64 + lane;
    vtu = (const uint4*)(Vt + (size_t)h*((size_t)n<<4)) + (size_t)(tile0>>1)*64 + lane;
    kcA = ktl[0]; kcB = ktl[64];      // chunk 0 K frags
    vCur = vtu[0];                    // V(0)
    vPrev = vCur;                     // defined; overwritten before first use
  }

  for (int c = 0; c < nch; ++c){
    // -------- half A: m computes S(c) (pure MFMA+write)  ||  v exps S(c-1)
    if (mw){
      const fp8x8 a0 = (fp8x8)kcA.x, a1 = (fp8x8)kcA.y;
      const fp8x8 b0 = (fp8x8)kcB.x, b1 = (fp8x8)kcB.y;
      f32x4 s = __builtin_amdgcn_mfma_f32_16x16x32_fp8_fp8(a0, qf0, z, 0,0,0);
      s = __builtin_amdgcn_mfma_f32_16x16x32_fp8_fp8(a1, qf1, s, 0,0,0);
      f32x4 u = __builtin_amdgcn_mfma_f32_16x16x32_fp8_fp8(b0, qf0, z, 0,0,0);
      u = __builtin_amdgcn_mfma_f32_16x16x32_fp8_fp8(b1, qf1, u, 0,0,0);
      *(f32x4*)(sbp + (c&1)*8192       ) = s;
      *(f32x4*)(sbp + (c&1)*8192 + 1024) = u;
      kcA = ktl[128]; kcB = ktl[192]; ktl += 128;   // chunk c+1 (1-deep prefetch)
    } else if (c > 0){
      f32x4 s = *(const f32x4*)(sbp + ((c-1)&1)*8192       );
      f32x4 u = *(const f32x4*)(sbp + ((c-1)&1)*8192 + 1024);
      float e0 = __builtin_amdgcn_exp2f(s[0]);
      float e1 = __builtin_amdgcn_exp2f(s[1]);
      float e2 = __builtin_amdgcn_exp2f(s[2]);
      float e3 = __builtin_amdgcn_exp2f(s[3]);
      float f0 = __builtin_amdgcn_exp2f(u[0]);
      float f1 = __builtin_amdgcn_exp2f(u[1]);
      float f2 = __builtin_amdgcn_exp2f(u[2]);
      float f3 = __builtin_amdgcn_exp2f(u[3]);
      uint4 pq = make_uint4(pack2bf_t(e0,e1), pack2bf_t(e2,e3),
                            pack2bf_t(f0,f1), pack2bf_t(f2,f3));
      *(uint4*)(pbp + ((c-1)&1)*4096) = pq;
    }
    __syncthreads();
    // -------- half B: m consumes P(c-1) with V(c-1)
    if (mw){
      if (c > 0){
        union { uint4 uu; bf16x8 v; } pq; pq.uu = *(const uint4*)(pbp + ((c-1)&1)*4096);
        union { uint4 uu; bf16x8 v; } vf; vf.uu = vPrev;
        o  = __builtin_amdgcn_mfma_f32_16x16x32_bf16(pq.v, vf.v,  o,  0,0,0);
        la = __builtin_amdgcn_mfma_f32_16x16x32_bf16(pq.v, vones, la, 0,0,0);
      }
      vPrev = vCur; vCur = vtu[64]; vtu += 64;      // roll V pipeline
    }
  }
  // -------- tail: exp + PV for the final chunk (nch-1)
  if (!mw){
    const int b = (nch-1)&1;
    f32x4 s = *(const f32x4*)(sbp + b*8192       );
    f32x4 u = *(const f32x4*)(sbp + b*8192 + 1024);
    float e0 = __builtin_amdgcn_exp2f(s[0]);
    float e1 = __builtin_amdgcn_exp2f(s[1]);
    float e2 = __builtin_amdgcn_exp2f(s[2]);
    float e3 = __builtin_amdgcn_exp2f(s[3]);
    float f0 = __builtin_amdgcn_exp2f(u[0]);
    float f1 = __builtin_amdgcn_exp2f(u[1]);
    float f2 = __builtin_amdgcn_exp2f(u[2]);
    float f3 = __builtin_amdgcn_exp2f(u[3]);
    uint4 pq = make_uint4(pack2bf_t(e0,e1), pack2bf_t(e2,e3),
                          pack2bf_t(f0,f1), pack2bf_t(f2,f3));
    *(uint4*)(pbp + b*4096) = pq;
  }
  __syncthreads();
  if (mw){
    const int b = (nch-1)&1;
    union { uint4 uu; bf16x8 v; } pq; pq.uu = *(const uint4*)(pbp + b*4096);
    union { uint4 uu; bf16x8 v; } vf; vf.uu = vPrev;   // V(nch-1)
    o  = __builtin_amdgcn_mfma_f32_16x16x32_bf16(pq.v, vf.v,  o,  0,0,0);
    la = __builtin_amdgcn_mfma_f32_16x16x32_bf16(pq.v, vones, la, 0,0,0);
  }

  // -------- cross-key-half reduction (2 m-waves share each row-half)
  if (mw && kh == 1){
    float* q = &part[rh][lane][0];
    q[0]=o[0];  q[1]=o[1];  q[2]=o[2];  q[3]=o[3];
    q[4]=la[0]; q[5]=la[1]; q[6]=la[2]; q[7]=la[3];
  }
  __syncthreads();
  if (mw && kh == 0){
    const float* q = &part[rh][lane][0];
    o[0] +=q[0]; o[1] +=q[1]; o[2] +=q[2]; o[3] +=q[3];
    la[0]+=q[4]; la[1]+=q[5]; la[2]+=q[6]; la[3]+=q[7];
    #pragma unroll
    for (int reg = 0; reg < 4; ++reg){
      int i = rh*16 + quad*4 + reg;
      out[(size_t)(i0 + i)*64 + h*16 + l16] = o[reg] / la[reg];
    }
  }
}

extern "C" void kernel_launch(void* const* d_in, const int* in_sizes, int n_in,
                              void* d_out, int out_size, void* d_ws, size_t ws_size,
                              hipStream_t stream) {
  const float* x  = (const float*)d_in[0];
  const float* Wq = (const float*)d_in[1];
  const float* bq = (const float*)d_in[2];
  const float* Wk = (const float*)d_in[3];
  const float* bk = (const float*)d_in[4];
  const float* Wv = (const float*)d_in[5];
  const float* bv = (const float*)d_in[6];
  float* out = (float*)d_out;

  const int n = in_sizes[0] / 64;   // 8192

  unsigned char* Qfr  = (unsigned char*)d_ws;                       // NH*n*64 B frag tiles (Q)
  unsigned char* Kt   = Qfr + (size_t)NH*n*64;                      // NH*n*64 B frag tiles (K)
  unsigned short* Vt  = (unsigned short*)(Kt + (size_t)NH*n*64);    // NH*n*16 u16 frag tiles (chunk-interleaved)
  unsigned short* WF  = Vt + (size_t)NH*n*16;                       // NH*18*64*8 u16 frags
  float* bias_s       = (float*)(WF + (size_t)NH*18*64*8);          // NH*128 f32

  wprep_kernel<<<NH, 256, 0, stream>>>(Wq, bq, Wk, bk, Wv, WF, bias_s, n);
  proj_kernel<<<dim3(n/64, NH), 256, 0, stream>>>(x, bv, WF, bias_s, Qfr, Kt, Vt, n);
  attn_kernel<<<dim3((n/32)*NH), 512, 0, stream>>>(Qfr, Kt, Vt, out, n);
}

// Round 11
// 151.688 us; speedup vs baseline: 1.0656x; 1.0656x over previous
//
#include <hip/hip_runtime.h>

typedef __attribute__((ext_vector_type(4))) float f32x4;
typedef __attribute__((ext_vector_type(16))) float f32x16;
typedef __attribute__((ext_vector_type(8))) short bf16x8;
typedef __attribute__((ext_vector_type(8))) int int32x8;
typedef __attribute__((ext_vector_type(2))) int int32x2;
typedef long fp8x8;

#define NH 4

// round-to-nearest-even f32 -> bf16
static __device__ __forceinline__ unsigned short f2bf(float f){
  unsigned u = __float_as_uint(f);
  u += 0x7FFFu + ((u >> 16) & 1u);
  return (unsigned short)(u >> 16);
}

// pack two f32 -> two bf16 (round-half-up) in one uint (low = a)
static __device__ __forceinline__ unsigned pack2bf(float a, float b){
  return __builtin_amdgcn_perm(__float_as_uint(b) + 0x8000u,
                               __float_as_uint(a) + 0x8000u, 0x07060302u);
}

// pack two f32 -> two bf16 TRUNCATING (1 v_perm). Used only for P: the same
// truncated P feeds both O=P*V and l=P*1 (ones column), so bias cancels.
static __device__ __forceinline__ unsigned pack2bf_t(float a, float b){
  return __builtin_amdgcn_perm(__float_as_uint(b), __float_as_uint(a), 0x07060302u);
}

// pack 4 floats into 4 fp8(e4m3) bytes of one int (byte0 = a)
static __device__ __forceinline__ int pack_fp8x4(float a, float b, float c, float d){
  int w = __builtin_amdgcn_cvt_pk_fp8_f32(a, b, 0, false);
  w     = __builtin_amdgcn_cvt_pk_fp8_f32(c, d, w, true);
  return w;
}

static __device__ __forceinline__ uint4 selv(bool c, uint4 a, uint4 b){
  return make_uint4(c?a.x:b.x, c?a.y:b.y, c?a.z:b.z, c?a.w:b.w);
}

// ---------------- weight-prep kernel (unchanged, proven) ----------------
__global__ __launch_bounds__(256) void wprep_kernel(
    const float* __restrict__ Wq, const float* __restrict__ bq,
    const float* __restrict__ Wk, const float* __restrict__ bk,
    const float* __restrict__ Wv,
    unsigned short* __restrict__ WF, float* __restrict__ bias_s, int n)
{
  __shared__ unsigned short wqT[64*72];
  __shared__ unsigned short wkT[64*72];
  __shared__ unsigned short wvT[16*72];

  const int t = threadIdx.x;
  const int h = blockIdx.x;
  const float S1 = 0.4246609001f; // sqrt((1/sqrt(64)) * log2(e))
  const int f = t >> 2, eg = t & 3;

  {
    const float4* g = (const float4*)(Wq + h*4096 + f*64 + eg*16);
    #pragma unroll
    for (int p = 0; p < 4; ++p){
      float4 d = g[p]; int e0 = eg*16 + p*4;
      wqT[(e0+0)*72 + f] = f2bf(d.x * S1);
      wqT[(e0+1)*72 + f] = f2bf(d.y * S1);
      wqT[(e0+2)*72 + f] = f2bf(d.z * S1);
      wqT[(e0+3)*72 + f] = f2bf(d.w * S1);
    }
  }
  {
    const float4* g = (const float4*)(Wk + h*4096 + f*64 + eg*16);
    #pragma unroll
    for (int p = 0; p < 4; ++p){
      float4 d = g[p]; int e0 = eg*16 + p*4;
      wkT[(e0+0)*72 + f] = f2bf(d.x * S1);
      wkT[(e0+1)*72 + f] = f2bf(d.y * S1);
      wkT[(e0+2)*72 + f] = f2bf(d.z * S1);
      wkT[(e0+3)*72 + f] = f2bf(d.w * S1);
    }
  }
  {
    float4 d = *(const float4*)(Wv + h*1024 + f*16 + eg*4);
    int d0 = eg*4;
    wvT[(d0+0)*72 + f] = f2bf(d.x);
    wvT[(d0+1)*72 + f] = f2bf(d.y);
    wvT[(d0+2)*72 + f] = f2bf(d.z);
    wvT[(d0+3)*72 + f] = f2bf(d.w);
  }
  if (t < 64)       bias_s[h*128 + t] = bq[h*64 + t] * S1;
  else if (t < 128) bias_s[h*128 + t] = bk[h*64 + (t-64)] * S1;
  __syncthreads();

  const int lane = t & 63, w = t >> 6;
  const int quad = lane >> 4, l16 = lane & 15;
  for (int s = w; s < 18; s += 4){
    const unsigned short* src;
    if (s < 8){      int et = s>>1,     ks = s&1;     src = wqT + (et*16+l16)*72 + ks*32 + quad*8; }
    else if (s < 16){int ft = (s-8)>>1, ks = (s-8)&1; src = wkT + (ft*16+l16)*72 + ks*32 + quad*8; }
    else {           int ks = s-16;                   src = wvT + l16*72 + ks*32 + quad*8; }
    uint4 v = *(const uint4*)src;
    *(uint4*)(WF + ((size_t)(h*18 + s)*64 + lane)*8) = v;
  }
}

// ---------------- projection kernel ----------------
// R26: epilogues rewritten for the MX/32x32 attn layouts.
// Qfr: MX B-frags. per 32-row group: lane (qrow=lane&31, kh=lane>>5) holds
//      Q[qrow][f = kh*32 .. +31] as 32 fp8 bytes (dense 32B/lane).
// Kt : MX A-frags. per 32-key group: lane (key=lane&31, kh) holds
//      K[key][f = kh*32 .. +31] (32 fp8 bytes).
// Vt : compact 32x32x16-bf16 B-frags. per 16-key tile: lane c+16*h (c<16)
//      holds bf16 V[k=h*8+j][c], j=0..7 (16B). (cols 16..31 synthesized
//      in-register in attn: col16 = ones -> free la; rest 0.)
__global__ __launch_bounds__(256) void proj_kernel(
    const float* __restrict__ x, const float* __restrict__ bv,
    const unsigned short* __restrict__ WF, const float* __restrict__ bias_s,
    unsigned char* __restrict__ Qfr, unsigned char* __restrict__ Kt,
    unsigned short* __restrict__ Vt, int n)
{
  __shared__ unsigned short xf[8*64*8];
  __shared__ float bql[64], bkl[64], bvl[16];

  const int t  = threadIdx.x;
  const int h  = blockIdx.y;
  const int r0 = blockIdx.x * 64;

  {
    const int r = t >> 2, cg4 = t & 3;
    const float4* g = (const float4*)(x + (size_t)(r0 + r)*64 + cg4*16);
    float4 a = g[0], b = g[1], c = g[2], d = g[3];
    unsigned u0 = pack2bf(a.x,a.y), u1 = pack2bf(a.z,a.w);
    unsigned u2 = pack2bf(b.x,b.y), u3 = pack2bf(b.z,b.w);
    unsigned u4 = pack2bf(c.x,c.y), u5 = pack2bf(c.z,c.w);
    unsigned u6 = pack2bf(d.x,d.y), u7 = pack2bf(d.z,d.w);
    const int it = r >> 4, l16r = r & 15, ks = cg4 >> 1, q0 = (cg4 & 1)*2;
    uint4* dst0 = (uint4*)(xf + ((it*2+ks)*64 + q0*16     + l16r)*8);
    uint4* dst1 = (uint4*)(xf + ((it*2+ks)*64 + (q0+1)*16 + l16r)*8);
    *dst0 = make_uint4(u0,u1,u2,u3);
    *dst1 = make_uint4(u4,u5,u6,u7);
  }
  if (t < 64)        bql[t]     = bias_s[h*128 + t];
  else if (t < 128)  bkl[t-64]  = bias_s[h*128 + t];
  else if (t < 144)  bvl[t-128] = bv[h*16 + (t-128)];
  __syncthreads();

  const int lane = t & 63, w = t >> 6;
  const int quad = lane >> 4, l16 = lane & 15;

  bf16x8 xa[8];
  #pragma unroll
  for (int i = 0; i < 8; ++i)
    xa[i] = *(const bf16x8*)(xf + (i*64 + lane)*8);

  const unsigned short* WFh = WF + (size_t)h*18*64*8;
  bf16x8 wq0 = *(const bf16x8*)(WFh + ((size_t)(     w*2 + 0)*64 + lane)*8);
  bf16x8 wq1 = *(const bf16x8*)(WFh + ((size_t)(     w*2 + 1)*64 + lane)*8);
  bf16x8 wk0 = *(const bf16x8*)(WFh + ((size_t)(8  + w*2 + 0)*64 + lane)*8);
  bf16x8 wk1 = *(const bf16x8*)(WFh + ((size_t)(8  + w*2 + 1)*64 + lane)*8);
  bf16x8 wv0 = *(const bf16x8*)(WFh + ((size_t)16*64 + lane)*8);
  bf16x8 wv1 = *(const bf16x8*)(WFh + ((size_t)17*64 + lane)*8);

  const f32x4 z = {0.f,0.f,0.f,0.f};
  f32x4 accQ[4] = {z,z,z,z};   // Q^T: rows e (tile w), cols Q-row (tile it)
  f32x4 accK[4] = {z,z,z,z};   // K^T: rows f (tile w), cols key (tile tt)
  f32x4 accV = z;

  #pragma unroll
  for (int it = 0; it < 4; ++it){
    accQ[it] = __builtin_amdgcn_mfma_f32_16x16x32_bf16(wq0, xa[it*2+0], accQ[it], 0,0,0);
    accQ[it] = __builtin_amdgcn_mfma_f32_16x16x32_bf16(wq1, xa[it*2+1], accQ[it], 0,0,0);
  }
  #pragma unroll
  for (int tt = 0; tt < 4; ++tt){
    accK[tt] = __builtin_amdgcn_mfma_f32_16x16x32_bf16(wk0, xa[tt*2+0], accK[tt], 0,0,0);
    accK[tt] = __builtin_amdgcn_mfma_f32_16x16x32_bf16(wk1, xa[tt*2+1], accK[tt], 0,0,0);
  }
  accV = __builtin_amdgcn_mfma_f32_16x16x32_bf16(xa[w*2+0], wv0, accV, 0,0,0);
  accV = __builtin_amdgcn_mfma_f32_16x16x32_bf16(xa[w*2+1], wv1, accV, 0,0,0);

  const int kh    = w >> 1;                 // f-half (e>>5)
  const int ebyte = (w & 1)*16 + quad*4;    // f & 31 (4B aligned)

  // ---- Q^T tiles -> Qfr MX B-frag bytes: Q[qrow][f]
  {
    const int e0 = w*16 + quad*4;
    const float b0 = bql[e0], b1 = bql[e0+1], b2 = bql[e0+2], b3 = bql[e0+3];
    #pragma unroll
    for (int it = 0; it < 4; ++it){
      unsigned o = pack_fp8x4(accQ[it][0]+b0, accQ[it][1]+b1,
                              accQ[it][2]+b2, accQ[it][3]+b3);
      const int qg = (r0 >> 5) + (it >> 1);
      const int lq = (it & 1)*16 + l16 + 32*kh;
      *(unsigned*)(Qfr + (size_t)h*((size_t)n<<6)
                       + ((size_t)(qg*64 + lq))*32 + ebyte) = o;
    }
  }
  // ---- K^T tiles -> Kt MX A-frag bytes: K[key][f]
  {
    const int f0 = w*16 + quad*4;
    const float bk0 = bkl[f0], bk1 = bkl[f0+1], bk2 = bkl[f0+2], bk3 = bkl[f0+3];
    #pragma unroll
    for (int tt = 0; tt < 4; ++tt){
      unsigned o = pack_fp8x4(accK[tt][0]+bk0, accK[tt][1]+bk1,
                              accK[tt][2]+bk2, accK[tt][3]+bk3);
      const int kg = (r0 >> 5) + (tt >> 1);
      const int lk = (tt & 1)*16 + l16 + 32*kh;
      *(unsigned*)(Kt + (size_t)h*((size_t)n<<6)
                      + ((size_t)(kg*64 + lk))*32 + ebyte) = o;
    }
  }
  // ---- V tile (it=w): C[key=quad*4+reg][d=l16] -> compact Vt B-frags.
  // target ushort idx = (T*32 + c + 16*(key>>3))*8 + (key&7); c = l16.
  {
    const int T = (r0 >> 4) + w;
    float bvv = bvl[l16];
    #pragma unroll
    for (int reg = 0; reg < 4; ++reg){
      const int key = quad*4 + reg;
      Vt[(size_t)h*((size_t)n<<4)
         + ((size_t)(T*32 + l16 + 16*(key>>3)))*8 + (key & 7)]
        = f2bf(accV[reg] + bvv);
    }
  }
}

// ---------------- flash attention kernel ----------------
// R26: MX QK + ones-augmented 32x32 PV. R25 falsified wave specialization
// (2x regression: per-chunk barriers serialize); overlap family closed.
// This round cuts the MATRIX serial term instead: QK via
// mfma_scale_f32_32x32x64_f8f6f4 (K=64 = full reduction dim, unit e8m0
// scales = plain fp8 matmul at the ~4.7PF MX rate): 2 instr/chunk vs 16.
// PV via 32x32x16 bf16 with V augmented by a ones column (col 16): la is
// computed in the SAME MFMA -> 4 instr/chunk, no separate la MFMAs.
// S-frag (col=lane&31=qrow, row=key(reg,half)) feeds PV's A-frag
// (row=lane&31=qrow, k=(lane>>5)*8+j) after exp/pack with exactly 4
// permlane32_swap per row-group (lane<->lane+32 is the only exchange;
// element-mapping verified). Matrix cyc/chunk 465->272 (-42%).
// 64-row blocks, 8 waves = key octants, 32 chunks each: R19 geometry.
__global__ __launch_bounds__(512, 4) void attn_kernel(
    const unsigned char* __restrict__ Qfr, const unsigned char* __restrict__ Kt,
    const unsigned short* __restrict__ Vt, float* __restrict__ out, int n)
{
  __shared__ float part[7][64][33];   // 59 KB (32 payload + pad)

  const int tid  = threadIdx.x;
  const int lane = tid & 63;
  const int jq   = tid >> 6;          // key octant

  #pragma unroll 1
  for (int i = 0; i < jq; ++i) __builtin_amdgcn_s_sleep(3);

  const int bid  = blockIdx.x;
  const int h    = bid & 3;
  const int iblk = bid >> 2;
  const int i0   = iblk*64;
  const int c31  = lane & 31, hl = lane >> 5;
  const int nch  = n >> 8;            // 32-key chunks per octant (32)

  // Q MX B-frags, 2 row-groups (dense 32B/lane)
  const int32x8* qp = (const int32x8*)(Qfr + (size_t)h*((size_t)n<<6));
  const int qg0 = i0 >> 5;
  const int32x8 qA = qp[(size_t)qg0*64 + lane];
  const int32x8 qB = qp[(size_t)(qg0+1)*64 + lane];

  // K MX A-frags: group g at kp[g*64]
  const int32x8* kp = (const int32x8*)(Kt + (size_t)h*((size_t)n<<6))
                      + (size_t)(jq*32)*64 + lane;
  // V compact frags: tile T at vp[T*32 + vlane]
  const int vlane = (lane & 15) + ((lane & 32) >> 1);
  const uint4* vp = (const uint4*)(Vt + (size_t)h*((size_t)n<<4))
                    + (size_t)(jq*64)*32 + vlane;

  const bool  vload = (c31 < 16);
  const unsigned one2 = 0x3F803F80u;
  const uint4 vsel = (c31 == 16) ? make_uint4(one2,one2,one2,one2)
                                 : make_uint4(0,0,0,0);

  const f32x16 z16 = {0,0,0,0,0,0,0,0,0,0,0,0,0,0,0,0};
  f32x16 acc0 = z16, acc1 = z16;

  int32x8 ka = kp[0], kb = kp[64];

#define PVSTEP(S, ACC, VF0, VF1)                                              \
  {                                                                           \
    float p0  = __builtin_amdgcn_exp2f(S[0]);                                 \
    float p1  = __builtin_amdgcn_exp2f(S[1]);                                 \
    float p2  = __builtin_amdgcn_exp2f(S[2]);                                 \
    float p3  = __builtin_amdgcn_exp2f(S[3]);                                 \
    float p4  = __builtin_amdgcn_exp2f(S[4]);                                 \
    float p5  = __builtin_amdgcn_exp2f(S[5]);                                 \
    float p6  = __builtin_amdgcn_exp2f(S[6]);                                 \
    float p7  = __builtin_amdgcn_exp2f(S[7]);                                 \
    float p8  = __builtin_amdgcn_exp2f(S[8]);                                 \
    float p9  = __builtin_amdgcn_exp2f(S[9]);                                 \
    float p10 = __builtin_amdgcn_exp2f(S[10]);                                \
    float p11 = __builtin_amdgcn_exp2f(S[11]);                                \
    float p12 = __builtin_amdgcn_exp2f(S[12]);                                \
    float p13 = __builtin_amdgcn_exp2f(S[13]);                                \
    float p14 = __builtin_amdgcn_exp2f(S[14]);                                \
    float p15 = __builtin_amdgcn_exp2f(S[15]);                                \
    unsigned u0 = pack2bf_t(p0,p1),   u1 = pack2bf_t(p2,p3);                  \
    unsigned u2 = pack2bf_t(p4,p5),   u3 = pack2bf_t(p6,p7);                  \
    unsigned u4 = pack2bf_t(p8,p9),   u5 = pack2bf_t(p10,p11);                \
    unsigned u6 = pack2bf_t(p12,p13), u7 = pack2bf_t(p14,p15);                \
    int32x2 r01 = __builtin_amdgcn_permlane32_swap((int)u0,(int)u2,false,false);\
    int32x2 r23 = __builtin_amdgcn_permlane32_swap((int)u1,(int)u3,false,false);\
    int32x2 r45 = __builtin_amdgcn_permlane32_swap((int)u4,(int)u6,false,false);\
    int32x2 r67 = __builtin_amdgcn_permlane32_swap((int)u5,(int)u7,false,false);\
    union { uint4 uu; bf16x8 v; } pa1, pa2;                                   \
    pa1.uu = make_uint4(r01[0], r23[0], r01[1], r23[1]);                      \
    pa2.uu = make_uint4(r45[0], r67[0], r45[1], r67[1]);                      \
    ACC = __builtin_amdgcn_mfma_f32_32x32x16_bf16(pa1.v, VF0, ACC, 0,0,0);    \
    ACC = __builtin_amdgcn_mfma_f32_32x32x16_bf16(pa2.v, VF1, ACC, 0,0,0);    \
  }

#define CHUNKV(KF, VIDX)                                                      \
  {                                                                           \
    union { uint4 uu; bf16x8 v; } v0u, v1u;                                   \
    v0u.uu = selv(vload, vp[(VIDX)],      vsel);                              \
    v1u.uu = selv(vload, vp[(VIDX) + 32], vsel);                              \
    f32x16 s0 = __builtin_amdgcn_mfma_scale_f32_32x32x64_f8f6f4(              \
        KF, qA, z16, 0, 0, 0, 0x7F7F7F7F, 0, 0x7F7F7F7F);                     \
    f32x16 s1 = __builtin_amdgcn_mfma_scale_f32_32x32x64_f8f6f4(              \
        KF, qB, z16, 0, 0, 0, 0x7F7F7F7F, 0, 0x7F7F7F7F);                     \
    PVSTEP(s0, acc0, v0u.v, v1u.v)                                            \
    PVSTEP(s1, acc1, v0u.v, v1u.v)                                            \
  }

  // main loop, unrolled x2, 1-chunk-ahead K reload, V loaded per chunk
  for (int c = 0; c < nch - 2; c += 2){
    CHUNKV(ka, 0)
    ka = kp[128];
    CHUNKV(kb, 64)
    kb = kp[192];
    kp += 128; vp += 128;
    // interleave hint: 12 MFMA : ~130 VALU per 2-chunk body
    #pragma unroll
    for (int g = 0; g < 12; ++g){
      __builtin_amdgcn_sched_group_barrier(0x008, 1, 0);   // 1 MFMA
      __builtin_amdgcn_sched_group_barrier(0x002, 10, 0);  // 10 VALU
    }
  }
  CHUNKV(ka, 0)
  CHUNKV(kb, 64)
#undef CHUNKV
#undef PVSTEP

  // ---- cross-wave reduction (8 key octants) ----
  if (jq > 0){
    float* p = &part[jq-1][lane][0];
    #pragma unroll
    for (int i = 0; i < 16; ++i) p[i]      = acc0[i];
    #pragma unroll
    for (int i = 0; i < 16; ++i) p[16 + i] = acc1[i];
  }
  __syncthreads();

  if (jq == 0){
    #pragma unroll
    for (int q = 0; q < 7; ++q){
      const float* r = &part[q][lane][0];
      #pragma unroll
      for (int i = 0; i < 16; ++i) acc0[i] += r[i];
      #pragma unroll
      for (int i = 0; i < 16; ++i) acc1[i] += r[16 + i];
    }
    // la lives in col 16 of the augmented output; broadcast within half.
    const int lsrc = 16 | (lane & 32);
    #pragma unroll
    for (int i = 0; i < 16; ++i){
      float la0 = __shfl(acc0[i], lsrc, 64);
      float la1 = __shfl(acc1[i], lsrc, 64);
      const int row = (i & 3) + 8*(i >> 2) + 4*hl;
      if (c31 < 16){
        out[(size_t)(i0 +      row)*64 + h*16 + c31] = acc0[i] / la0;
        out[(size_t)(i0 + 32 + row)*64 + h*16 + c31] = acc1[i] / la1;
      }
    }
  }
}

extern "C" void kernel_launch(void* const* d_in, const int* in_sizes, int n_in,
                              void* d_out, int out_size, void* d_ws, size_t ws_size,
                              hipStream_t stream) {
  const float* x  = (const float*)d_in[0];
  const float* Wq = (const float*)d_in[1];
  const float* bq = (const float*)d_in[2];
  const float* Wk = (const float*)d_in[3];
  const float* bk = (const float*)d_in[4];
  const float* Wv = (const float*)d_in[5];
  const float* bv = (const float*)d_in[6];
  float* out = (float*)d_out;

  const int n = in_sizes[0] / 64;   // 8192

  unsigned char* Qfr  = (unsigned char*)d_ws;                       // NH*n*64 B (MX B-frags)
  unsigned char* Kt   = Qfr + (size_t)NH*n*64;                      // NH*n*64 B (MX A-frags)
  unsigned short* Vt  = (unsigned short*)(Kt + (size_t)NH*n*64);    // NH*n*16 u16 (compact V frags)
  unsigned short* WF  = Vt + (size_t)NH*n*16;                       // NH*18*64*8 u16 frags
  float* bias_s       = (float*)(WF + (size_t)NH*18*64*8);          // NH*128 f32

  wprep_kernel<<<NH, 256, 0, stream>>>(Wq, bq, Wk, bk, Wv, WF, bias_s, n);
  proj_kernel<<<dim3(n/64, NH), 256, 0, stream>>>(x, bv, WF, bias_s, Qfr, Kt, Vt, n);
  attn_kernel<<<dim3((n/64)*NH), 512, 0, stream>>>(Qfr, Kt, Vt, out, n);
}

// Round 12
// 123.109 us; speedup vs baseline: 1.3130x; 1.2321x over previous
//
#include <hip/hip_runtime.h>

typedef __attribute__((ext_vector_type(4))) float f32x4;
typedef __attribute__((ext_vector_type(16))) float f32x16;
typedef __attribute__((ext_vector_type(8))) short bf16x8;
typedef __attribute__((ext_vector_type(8))) int int32x8;
typedef __attribute__((ext_vector_type(2))) int int32x2;
typedef long fp8x8;

#define NH 4

// round-to-nearest-even f32 -> bf16
static __device__ __forceinline__ unsigned short f2bf(float f){
  unsigned u = __float_as_uint(f);
  u += 0x7FFFu + ((u >> 16) & 1u);
  return (unsigned short)(u >> 16);
}

// pack two f32 -> two bf16 (round-half-up) in one uint (low = a)
static __device__ __forceinline__ unsigned pack2bf(float a, float b){
  return __builtin_amdgcn_perm(__float_as_uint(b) + 0x8000u,
                               __float_as_uint(a) + 0x8000u, 0x07060302u);
}

// pack two f32 -> two bf16 TRUNCATING (1 v_perm). Used only for P: the same
// truncated P feeds both O=P*V and l=P*1 (ones column), so bias cancels.
static __device__ __forceinline__ unsigned pack2bf_t(float a, float b){
  return __builtin_amdgcn_perm(__float_as_uint(b), __float_as_uint(a), 0x07060302u);
}

// pack 4 floats into 4 fp8(e4m3) bytes of one int (byte0 = a)
static __device__ __forceinline__ int pack_fp8x4(float a, float b, float c, float d){
  int w = __builtin_amdgcn_cvt_pk_fp8_f32(a, b, 0, false);
  w     = __builtin_amdgcn_cvt_pk_fp8_f32(c, d, w, true);
  return w;
}

static __device__ __forceinline__ uint4 selv(bool c, uint4 a, uint4 b){
  return make_uint4(c?a.x:b.x, c?a.y:b.y, c?a.z:b.z, c?a.w:b.w);
}

// ---------------- weight-prep kernel (unchanged, proven) ----------------
__global__ __launch_bounds__(256) void wprep_kernel(
    const float* __restrict__ Wq, const float* __restrict__ bq,
    const float* __restrict__ Wk, const float* __restrict__ bk,
    const float* __restrict__ Wv,
    unsigned short* __restrict__ WF, float* __restrict__ bias_s, int n)
{
  __shared__ unsigned short wqT[64*72];
  __shared__ unsigned short wkT[64*72];
  __shared__ unsigned short wvT[16*72];

  const int t = threadIdx.x;
  const int h = blockIdx.x;
  const float S1 = 0.4246609001f; // sqrt((1/sqrt(64)) * log2(e))
  const int f = t >> 2, eg = t & 3;

  {
    const float4* g = (const float4*)(Wq + h*4096 + f*64 + eg*16);
    #pragma unroll
    for (int p = 0; p < 4; ++p){
      float4 d = g[p]; int e0 = eg*16 + p*4;
      wqT[(e0+0)*72 + f] = f2bf(d.x * S1);
      wqT[(e0+1)*72 + f] = f2bf(d.y * S1);
      wqT[(e0+2)*72 + f] = f2bf(d.z * S1);
      wqT[(e0+3)*72 + f] = f2bf(d.w * S1);
    }
  }
  {
    const float4* g = (const float4*)(Wk + h*4096 + f*64 + eg*16);
    #pragma unroll
    for (int p = 0; p < 4; ++p){
      float4 d = g[p]; int e0 = eg*16 + p*4;
      wkT[(e0+0)*72 + f] = f2bf(d.x * S1);
      wkT[(e0+1)*72 + f] = f2bf(d.y * S1);
      wkT[(e0+2)*72 + f] = f2bf(d.z * S1);
      wkT[(e0+3)*72 + f] = f2bf(d.w * S1);
    }
  }
  {
    float4 d = *(const float4*)(Wv + h*1024 + f*16 + eg*4);
    int d0 = eg*4;
    wvT[(d0+0)*72 + f] = f2bf(d.x);
    wvT[(d0+1)*72 + f] = f2bf(d.y);
    wvT[(d0+2)*72 + f] = f2bf(d.z);
    wvT[(d0+3)*72 + f] = f2bf(d.w);
  }
  if (t < 64)       bias_s[h*128 + t] = bq[h*64 + t] * S1;
  else if (t < 128) bias_s[h*128 + t] = bk[h*64 + (t-64)] * S1;
  __syncthreads();

  const int lane = t & 63, w = t >> 6;
  const int quad = lane >> 4, l16 = lane & 15;
  for (int s = w; s < 18; s += 4){
    const unsigned short* src;
    if (s < 8){      int et = s>>1,     ks = s&1;     src = wqT + (et*16+l16)*72 + ks*32 + quad*8; }
    else if (s < 16){int ft = (s-8)>>1, ks = (s-8)&1; src = wkT + (ft*16+l16)*72 + ks*32 + quad*8; }
    else {           int ks = s-16;                   src = wvT + l16*72 + ks*32 + quad*8; }
    uint4 v = *(const uint4*)src;
    *(uint4*)(WF + ((size_t)(h*18 + s)*64 + lane)*8) = v;
  }
}

// ---------------- projection kernel (R26 layouts, proven correct) --------
// Qfr: MX B-frags. per 32-row group: lane (qrow=lane&31, kh=lane>>5) holds
//      Q[qrow][f = kh*32 .. +31] as 32 fp8 bytes (dense 32B/lane).
// Kt : MX A-frags. per 32-key group: lane (key=lane&31, kh) holds
//      K[key][f = kh*32 .. +31] (32 fp8 bytes).
// Vt : compact 32x32x16-bf16 B-frags. per 16-key tile: lane c+16*h (c<16)
//      holds bf16 V[k=h*8+j][c], j=0..7 (16B).
__global__ __launch_bounds__(256) void proj_kernel(
    const float* __restrict__ x, const float* __restrict__ bv,
    const unsigned short* __restrict__ WF, const float* __restrict__ bias_s,
    unsigned char* __restrict__ Qfr, unsigned char* __restrict__ Kt,
    unsigned short* __restrict__ Vt, int n)
{
  __shared__ unsigned short xf[8*64*8];
  __shared__ float bql[64], bkl[64], bvl[16];

  const int t  = threadIdx.x;
  const int h  = blockIdx.y;
  const int r0 = blockIdx.x * 64;

  {
    const int r = t >> 2, cg4 = t & 3;
    const float4* g = (const float4*)(x + (size_t)(r0 + r)*64 + cg4*16);
    float4 a = g[0], b = g[1], c = g[2], d = g[3];
    unsigned u0 = pack2bf(a.x,a.y), u1 = pack2bf(a.z,a.w);
    unsigned u2 = pack2bf(b.x,b.y), u3 = pack2bf(b.z,b.w);
    unsigned u4 = pack2bf(c.x,c.y), u5 = pack2bf(c.z,c.w);
    unsigned u6 = pack2bf(d.x,d.y), u7 = pack2bf(d.z,d.w);
    const int it = r >> 4, l16r = r & 15, ks = cg4 >> 1, q0 = (cg4 & 1)*2;
    uint4* dst0 = (uint4*)(xf + ((it*2+ks)*64 + q0*16     + l16r)*8);
    uint4* dst1 = (uint4*)(xf + ((it*2+ks)*64 + (q0+1)*16 + l16r)*8);
    *dst0 = make_uint4(u0,u1,u2,u3);
    *dst1 = make_uint4(u4,u5,u6,u7);
  }
  if (t < 64)        bql[t]     = bias_s[h*128 + t];
  else if (t < 128)  bkl[t-64]  = bias_s[h*128 + t];
  else if (t < 144)  bvl[t-128] = bv[h*16 + (t-128)];
  __syncthreads();

  const int lane = t & 63, w = t >> 6;
  const int quad = lane >> 4, l16 = lane & 15;

  bf16x8 xa[8];
  #pragma unroll
  for (int i = 0; i < 8; ++i)
    xa[i] = *(const bf16x8*)(xf + (i*64 + lane)*8);

  const unsigned short* WFh = WF + (size_t)h*18*64*8;
  bf16x8 wq0 = *(const bf16x8*)(WFh + ((size_t)(     w*2 + 0)*64 + lane)*8);
  bf16x8 wq1 = *(const bf16x8*)(WFh + ((size_t)(     w*2 + 1)*64 + lane)*8);
  bf16x8 wk0 = *(const bf16x8*)(WFh + ((size_t)(8  + w*2 + 0)*64 + lane)*8);
  bf16x8 wk1 = *(const bf16x8*)(WFh + ((size_t)(8  + w*2 + 1)*64 + lane)*8);
  bf16x8 wv0 = *(const bf16x8*)(WFh + ((size_t)16*64 + lane)*8);
  bf16x8 wv1 = *(const bf16x8*)(WFh + ((size_t)17*64 + lane)*8);

  const f32x4 z = {0.f,0.f,0.f,0.f};
  f32x4 accQ[4] = {z,z,z,z};
  f32x4 accK[4] = {z,z,z,z};
  f32x4 accV = z;

  #pragma unroll
  for (int it = 0; it < 4; ++it){
    accQ[it] = __builtin_amdgcn_mfma_f32_16x16x32_bf16(wq0, xa[it*2+0], accQ[it], 0,0,0);
    accQ[it] = __builtin_amdgcn_mfma_f32_16x16x32_bf16(wq1, xa[it*2+1], accQ[it], 0,0,0);
  }
  #pragma unroll
  for (int tt = 0; tt < 4; ++tt){
    accK[tt] = __builtin_amdgcn_mfma_f32_16x16x32_bf16(wk0, xa[tt*2+0], accK[tt], 0,0,0);
    accK[tt] = __builtin_amdgcn_mfma_f32_16x16x32_bf16(wk1, xa[tt*2+1], accK[tt], 0,0,0);
  }
  accV = __builtin_amdgcn_mfma_f32_16x16x32_bf16(xa[w*2+0], wv0, accV, 0,0,0);
  accV = __builtin_amdgcn_mfma_f32_16x16x32_bf16(xa[w*2+1], wv1, accV, 0,0,0);

  const int kh    = w >> 1;                 // f-half (e>>5)
  const int ebyte = (w & 1)*16 + quad*4;    // f & 31 (4B aligned)

  // ---- Q^T tiles -> Qfr MX B-frag bytes: Q[qrow][f]
  {
    const int e0 = w*16 + quad*4;
    const float b0 = bql[e0], b1 = bql[e0+1], b2 = bql[e0+2], b3 = bql[e0+3];
    #pragma unroll
    for (int it = 0; it < 4; ++it){
      unsigned o = pack_fp8x4(accQ[it][0]+b0, accQ[it][1]+b1,
                              accQ[it][2]+b2, accQ[it][3]+b3);
      const int qg = (r0 >> 5) + (it >> 1);
      const int lq = (it & 1)*16 + l16 + 32*kh;
      *(unsigned*)(Qfr + (size_t)h*((size_t)n<<6)
                       + ((size_t)(qg*64 + lq))*32 + ebyte) = o;
    }
  }
  // ---- K^T tiles -> Kt MX A-frag bytes: K[key][f]
  {
    const int f0 = w*16 + quad*4;
    const float bk0 = bkl[f0], bk1 = bkl[f0+1], bk2 = bkl[f0+2], bk3 = bkl[f0+3];
    #pragma unroll
    for (int tt = 0; tt < 4; ++tt){
      unsigned o = pack_fp8x4(accK[tt][0]+bk0, accK[tt][1]+bk1,
                              accK[tt][2]+bk2, accK[tt][3]+bk3);
      const int kg = (r0 >> 5) + (tt >> 1);
      const int lk = (tt & 1)*16 + l16 + 32*kh;
      *(unsigned*)(Kt + (size_t)h*((size_t)n<<6)
                      + ((size_t)(kg*64 + lk))*32 + ebyte) = o;
    }
  }
  // ---- V tile (it=w): C[key=quad*4+reg][d=l16] -> compact Vt B-frags.
  {
    const int T = (r0 >> 4) + w;
    float bvv = bvl[l16];
    #pragma unroll
    for (int reg = 0; reg < 4; ++reg){
      const int key = quad*4 + reg;
      Vt[(size_t)h*((size_t)n<<4)
         + ((size_t)(T*32 + l16 + 16*(key>>3)))*8 + (key & 7)]
        = f2bf(accV[reg] + bvv);
    }
  }
}

// ---------------- flash attention kernel ----------------
// R27 = R26 (MX QK + ones-augmented 32x32 PV; numerics PROVEN correct by
// R26's pass at identical absmax) with the register budget fixed.
// R26 post-mortem: the 2x regression was pure scratch spill -- allocator
// granted 64 VGPR against a ~110-VGPR body (WRITE_SIZE 21.9MB vs 2MB
// output = spill writes; FETCH +9MB = spill reads). Fixes:
//  (1) __launch_bounds__(512, 2): 256-VGPR budget, no strangling (R20
//      lesson applied correctly this time). Occupancy proven irrelevant
//      (R15-R21), so 1-2 blocks/CU is fine.
//  (2) SGB pin removed -- the 1:10 pattern stretched both f32x16 S-tiles'
//      live ranges across the whole 2-chunk body.
// Cycle model without spill: matrix 272 cyc/chunk (2 MX @68.7 + 4 bf16-PV
// @33.8) vs R19's 465; serial sum ~77k cyc/SIMD ~= 32us.
__global__ __launch_bounds__(512, 2) void attn_kernel(
    const unsigned char* __restrict__ Qfr, const unsigned char* __restrict__ Kt,
    const unsigned short* __restrict__ Vt, float* __restrict__ out, int n)
{
  __shared__ float part[7][64][33];   // 59 KB (32 payload + pad)

  const int tid  = threadIdx.x;
  const int lane = tid & 63;
  const int jq   = tid >> 6;          // key octant

  #pragma unroll 1
  for (int i = 0; i < jq; ++i) __builtin_amdgcn_s_sleep(3);

  const int bid  = blockIdx.x;
  const int h    = bid & 3;
  const int iblk = bid >> 2;
  const int i0   = iblk*64;
  const int c31  = lane & 31, hl = lane >> 5;
  const int nch  = n >> 8;            // 32-key chunks per octant (32)

  // Q MX B-frags, 2 row-groups (dense 32B/lane)
  const int32x8* qp = (const int32x8*)(Qfr + (size_t)h*((size_t)n<<6));
  const int qg0 = i0 >> 5;
  const int32x8 qA = qp[(size_t)qg0*64 + lane];
  const int32x8 qB = qp[(size_t)(qg0+1)*64 + lane];

  // K MX A-frags: group g at kp[g*64]
  const int32x8* kp = (const int32x8*)(Kt + (size_t)h*((size_t)n<<6))
                      + (size_t)(jq*32)*64 + lane;
  // V compact frags: tile T at vp[T*32 + vlane]
  const int vlane = (lane & 15) + ((lane & 32) >> 1);
  const uint4* vp = (const uint4*)(Vt + (size_t)h*((size_t)n<<4))
                    + (size_t)(jq*64)*32 + vlane;

  const bool  vload = (c31 < 16);
  const unsigned one2 = 0x3F803F80u;
  const uint4 vsel = (c31 == 16) ? make_uint4(one2,one2,one2,one2)
                                 : make_uint4(0,0,0,0);

  const f32x16 z16 = {0,0,0,0,0,0,0,0,0,0,0,0,0,0,0,0};
  f32x16 acc0 = z16, acc1 = z16;

  int32x8 ka = kp[0], kb = kp[64];

#define PVSTEP(S, ACC, VF0, VF1)                                              \
  {                                                                           \
    float p0  = __builtin_amdgcn_exp2f(S[0]);                                 \
    float p1  = __builtin_amdgcn_exp2f(S[1]);                                 \
    float p2  = __builtin_amdgcn_exp2f(S[2]);                                 \
    float p3  = __builtin_amdgcn_exp2f(S[3]);                                 \
    float p4  = __builtin_amdgcn_exp2f(S[4]);                                 \
    float p5  = __builtin_amdgcn_exp2f(S[5]);                                 \
    float p6  = __builtin_amdgcn_exp2f(S[6]);                                 \
    float p7  = __builtin_amdgcn_exp2f(S[7]);                                 \
    float p8  = __builtin_amdgcn_exp2f(S[8]);                                 \
    float p9  = __builtin_amdgcn_exp2f(S[9]);                                 \
    float p10 = __builtin_amdgcn_exp2f(S[10]);                                \
    float p11 = __builtin_amdgcn_exp2f(S[11]);                                \
    float p12 = __builtin_amdgcn_exp2f(S[12]);                                \
    float p13 = __builtin_amdgcn_exp2f(S[13]);                                \
    float p14 = __builtin_amdgcn_exp2f(S[14]);                                \
    float p15 = __builtin_amdgcn_exp2f(S[15]);                                \
    unsigned u0 = pack2bf_t(p0,p1),   u1 = pack2bf_t(p2,p3);                  \
    unsigned u2 = pack2bf_t(p4,p5),   u3 = pack2bf_t(p6,p7);                  \
    unsigned u4 = pack2bf_t(p8,p9),   u5 = pack2bf_t(p10,p11);                \
    unsigned u6 = pack2bf_t(p12,p13), u7 = pack2bf_t(p14,p15);                \
    int32x2 r01 = __builtin_amdgcn_permlane32_swap((int)u0,(int)u2,false,false);\
    int32x2 r23 = __builtin_amdgcn_permlane32_swap((int)u1,(int)u3,false,false);\
    int32x2 r45 = __builtin_amdgcn_permlane32_swap((int)u4,(int)u6,false,false);\
    int32x2 r67 = __builtin_amdgcn_permlane32_swap((int)u5,(int)u7,false,false);\
    union { uint4 uu; bf16x8 v; } pa1, pa2;                                   \
    pa1.uu = make_uint4(r01[0], r23[0], r01[1], r23[1]);                      \
    pa2.uu = make_uint4(r45[0], r67[0], r45[1], r67[1]);                      \
    ACC = __builtin_amdgcn_mfma_f32_32x32x16_bf16(pa1.v, VF0, ACC, 0,0,0);    \
    ACC = __builtin_amdgcn_mfma_f32_32x32x16_bf16(pa2.v, VF1, ACC, 0,0,0);    \
  }

#define CHUNKV(KF, VIDX)                                                      \
  {                                                                           \
    union { uint4 uu; bf16x8 v; } v0u, v1u;                                   \
    v0u.uu = selv(vload, vp[(VIDX)],      vsel);                              \
    v1u.uu = selv(vload, vp[(VIDX) + 32], vsel);                              \
    f32x16 s0 = __builtin_amdgcn_mfma_scale_f32_32x32x64_f8f6f4(              \
        KF, qA, z16, 0, 0, 0, 0x7F7F7F7F, 0, 0x7F7F7F7F);                     \
    PVSTEP(s0, acc0, v0u.v, v1u.v)                                            \
    f32x16 s1 = __builtin_amdgcn_mfma_scale_f32_32x32x64_f8f6f4(              \
        KF, qB, z16, 0, 0, 0, 0x7F7F7F7F, 0, 0x7F7F7F7F);                     \
    PVSTEP(s1, acc1, v0u.v, v1u.v)                                            \
  }

  // main loop, unrolled x2, 1-chunk-ahead K reload, V loaded per chunk
  for (int c = 0; c < nch - 2; c += 2){
    CHUNKV(ka, 0)
    ka = kp[128];
    CHUNKV(kb, 64)
    kb = kp[192];
    kp += 128; vp += 128;
  }
  CHUNKV(ka, 0)
  CHUNKV(kb, 64)
#undef CHUNKV
#undef PVSTEP

  // ---- cross-wave reduction (8 key octants) ----
  if (jq > 0){
    float* p = &part[jq-1][lane][0];
    #pragma unroll
    for (int i = 0; i < 16; ++i) p[i]      = acc0[i];
    #pragma unroll
    for (int i = 0; i < 16; ++i) p[16 + i] = acc1[i];
  }
  __syncthreads();

  if (jq == 0){
    #pragma unroll
    for (int q = 0; q < 7; ++q){
      const float* r = &part[q][lane][0];
      #pragma unroll
      for (int i = 0; i < 16; ++i) acc0[i] += r[i];
      #pragma unroll
      for (int i = 0; i < 16; ++i) acc1[i] += r[16 + i];
    }
    // la lives in col 16 of the augmented output; broadcast within half.
    const int lsrc = 16 | (lane & 32);
    #pragma unroll
    for (int i = 0; i < 16; ++i){
      float la0 = __shfl(acc0[i], lsrc, 64);
      float la1 = __shfl(acc1[i], lsrc, 64);
      const int row = (i & 3) + 8*(i >> 2) + 4*hl;
      if (c31 < 16){
        out[(size_t)(i0 +      row)*64 + h*16 + c31] = acc0[i] / la0;
        out[(size_t)(i0 + 32 + row)*64 + h*16 + c31] = acc1[i] / la1;
      }
    }
  }
}

extern "C" void kernel_launch(void* const* d_in, const int* in_sizes, int n_in,
                              void* d_out, int out_size, void* d_ws, size_t ws_size,
                              hipStream_t stream) {
  const float* x  = (const float*)d_in[0];
  const float* Wq = (const float*)d_in[1];
  const float* bq = (const float*)d_in[2];
  const float* Wk = (const float*)d_in[3];
  const float* bk = (const float*)d_in[4];
  const float* Wv = (const float*)d_in[5];
  const float* bv = (const float*)d_in[6];
  float* out = (float*)d_out;

  const int n = in_sizes[0] / 64;   // 8192

  unsigned char* Qfr  = (unsigned char*)d_ws;                       // NH*n*64 B (MX B-frags)
  unsigned char* Kt   = Qfr + (size_t)NH*n*64;                      // NH*n*64 B (MX A-frags)
  unsigned short* Vt  = (unsigned short*)(Kt + (size_t)NH*n*64);    // NH*n*16 u16 (compact V frags)
  unsigned short* WF  = Vt + (size_t)NH*n*16;                       // NH*18*64*8 u16 frags
  float* bias_s       = (float*)(WF + (size_t)NH*18*64*8);          // NH*128 f32

  wprep_kernel<<<NH, 256, 0, stream>>>(Wq, bq, Wk, bk, Wv, WF, bias_s, n);
  proj_kernel<<<dim3(n/64, NH), 256, 0, stream>>>(x, bv, WF, bias_s, Qfr, Kt, Vt, n);
  attn_kernel<<<dim3((n/64)*NH), 512, 0, stream>>>(Qfr, Kt, Vt, out, n);
}